// Round 5
// baseline (255.700 us; speedup 1.0000x reference)
//
#include <hip/hip_runtime.h>
#include <stdint.h>

typedef unsigned long long u64;
typedef unsigned int u32;
typedef float f32x4 __attribute__((ext_vector_type(4)));   // native vec: OK for NT builtins

constexpr int kC  = 256;
constexpr int kHW = 3136;             // 56*56 (divisible by 4 -> float4 quads never straddle n)
constexpr int kN  = 32;
constexpr int kP  = kN * kHW;         // 100352 spatial positions
constexpr int kTile = 256;            // positions per tile (f32x4 x 64 lanes)
constexpr int kBlkT = kP / kTile;     // 392 blocks (1.53/CU; MLP suffices)
constexpr int kRedBlk  = 8;           // reduce blocks
constexpr int kRedRows = kBlkT / kRedBlk;  // 49

// d_ws layout (bytes):
constexpr size_t OFF_T     = 0;        // u64 [4][256]  packed w-sign planes (plane-major)
constexpr size_t OFF_SCALE = 8192;     // f32 [256]
constexpr size_t OFF_SUMD  = 9216;     // i64 [256]  sum of dot
constexpr size_t OFF_SUMD2 = 11264;    // i64 [256]  sum of dot^2
constexpr size_t OFF_S     = 13312;    // u64 [4][kP] packed x-sign planes (SoA)
constexpr size_t OFF_PS    = 3224576;  // i32 [392][256] per-block summ partials
constexpr size_t OFF_PQ    = 4830208;  // i32 [392][256] per-block summ2 partials

struct alignas(16) U64x2 { u64 x, y; };

// ---------------------------------------------------------------------------
// Kernel A: w-prep. 16 blocks x 256. Builds T (w-sign planes) + scale;
// block 0 zeros the stat accumulators. ~2 us.
// ---------------------------------------------------------------------------
__global__ __launch_bounds__(256) void prep_kernel(
    const float* __restrict__ w, char* __restrict__ ws) {
  int t = threadIdx.x;
  int b = blockIdx.x;
  u64*   T     = (u64*)(ws + OFF_T);
  float* scale = (float*)(ws + OFF_SCALE);
  int kk = t >> 6, ln = t & 63;
  if (b == 0) {
    ((u64*)(ws + OFF_SUMD))[t]  = 0ull;
    ((u64*)(ws + OFF_SUMD2))[t] = 0ull;
  }
  __shared__ float part[4][16];
#pragma unroll
  for (int i = 0; i < 16; ++i) {
    int o = b * 16 + i;
    float v = w[o * kC + kk * 64 + ln];   // coalesced 256B/wave
    u64 m = __ballot(v >= 0.0f);
    float a = fabsf(v);
#pragma unroll
    for (int s = 32; s > 0; s >>= 1) a += __shfl_xor(a, s, 64);
    if (ln == 0) { T[kk * 256 + o] = m; part[kk][i] = a; }
  }
  __syncthreads();
  if (t < 16) {
    int o = b * 16 + t;
    scale[o] = (part[0][t] + part[1][t] + part[2][t] + part[3][t]) * (1.0f / 256.0f);
  }
}

// ---------------------------------------------------------------------------
// Kernel B: sign-pack, CONTIGUOUS layout. Block = 256-position tile; wave k
// owns plane k (channels 64k..64k+63); lane owns 4 consecutive positions.
// Each x load: f32x4/lane = 1 KB contiguous per wave-instruction. Lane
// accumulates 4 u64 masks in regs; S store is 32 B/lane contiguous.
// Plain loads: seed L3 for finalize.
// ---------------------------------------------------------------------------
__global__ __launch_bounds__(256) void pack_kernel(
    const float* __restrict__ x, const float* __restrict__ bias0,
    char* __restrict__ ws) {
  int t = threadIdx.x;
  int k    = __builtin_amdgcn_readfirstlane(t >> 6);  // wave-uniform plane
  int lane = t & 63;
  u32 p0 = (u32)blockIdx.x * (u32)kTile + 4u * (u32)lane;
  u32 n  = p0 / kHW;                   // per-lane (tiles may straddle n)
  u32 hw = p0 - n * kHW;               // multiple of 4 -> 16B-aligned
  const float* xp = x + (size_t)(n * kC + k * 64) * kHW + hw;
  const float* bp = bias0 + k * 64;    // uniform -> s_load

  u64 m0 = 0, m1 = 0, m2 = 0, m3 = 0;
#pragma unroll 8
  for (int i = 0; i < 64; ++i) {
    f32x4 v = *(const f32x4*)(xp + (size_t)i * kHW);
    float bc = bp[i];
    m0 |= (u64)(v.x + bc >= 0.0f) << i;
    m1 |= (u64)(v.y + bc >= 0.0f) << i;
    m2 |= (u64)(v.z + bc >= 0.0f) << i;
    m3 |= (u64)(v.w + bc >= 0.0f) << i;
  }
  u64* Sp = (u64*)(ws + OFF_S) + (size_t)k * kP + p0;
  U64x2 a; a.x = m0; a.y = m1;
  U64x2 b; b.x = m2; b.y = m3;
  *(U64x2*)Sp       = a;               // 32 B/lane contiguous
  *(U64x2*)(Sp + 2) = b;
}

// ---------------------------------------------------------------------------
// Kernel C: stats partials. Block = 256-position tile. Stage the 8 KB S tile
// into LDS coalesced (8 B/lane), then thread t = channel o popcounts all 256
// positions via LDS broadcast reads (~6 cyc vs ~200 cyc L2 uniform loads).
// Partials written coalesced, no contention.
// ---------------------------------------------------------------------------
__global__ __launch_bounds__(256) void stats_kernel(char* __restrict__ ws) {
  __shared__ u64 tile[4][kTile];       // 8 KB
  int t = threadIdx.x;
  u32 pb = blockIdx.x * (u32)kTile;
  const u64* S = (const u64*)(ws + OFF_S);
#pragma unroll
  for (int q = 0; q < 4; ++q) tile[q][t] = S[(size_t)q * kP + pb + t];

  const u64* T = (const u64*)(ws + OFF_T);
  u64 t0 = T[t], t1 = T[256 + t], t2 = T[512 + t], t3 = T[768 + t];
  __syncthreads();

  int summ = 0, summ2 = 0;
#pragma unroll 4
  for (int j = 0; j < kTile; ++j) {    // uniform j -> ds broadcast, no conflict
    int kx = __popcll(tile[0][j] ^ t0) + __popcll(tile[1][j] ^ t1) +
             __popcll(tile[2][j] ^ t2) + __popcll(tile[3][j] ^ t3);
    int mm = 128 - kx;
    summ  += mm;
    summ2 += mm * mm;
  }
  ((int*)(ws + OFF_PS))[blockIdx.x * 256 + t] = summ;   // coalesced 1 KB
  ((int*)(ws + OFF_PQ))[blockIdx.x * 256 + t] = summ2;  // coalesced 1 KB
}

// ---------------------------------------------------------------------------
// Kernel D: reduce partials. 8 blocks x 256; thread sums 49 rows of its
// channel column (coalesced, L2-resident), then ONE u64 atomic per stat
// (8 atomics/address -- proven negligible).
// ---------------------------------------------------------------------------
__global__ __launch_bounds__(256) void reduce_kernel(char* __restrict__ ws) {
  int t = threadIdx.x;
  int b = blockIdx.x;
  const int* PS = (const int*)(ws + OFF_PS);
  const int* PQ = (const int*)(ws + OFF_PQ);
  long long s = 0, q = 0;
#pragma unroll 7
  for (int r = 0; r < kRedRows; ++r) {
    int row = b * kRedRows + r;
    s += PS[row * 256 + t];
    q += PQ[row * 256 + t];
  }
  atomicAdd((u64*)(ws + OFF_SUMD) + t,  (u64)(long long)(2 * s));
  atomicAdd((u64*)(ws + OFF_SUMD2) + t, (u64)(long long)(4 * q));
}

// ---------------------------------------------------------------------------
// Kernel E: BN coefs + fused epilogue, CONTIGUOUS layout (mirrors pack).
// Wave k owns plane k's 64 output channels; lane owns 4 consecutive
// positions. Per channel-iter: f32x4 x load + f32x4 NT out store, each
// 1 KB contiguous per wave-instruction. S: 16 u64 in regs.
// T + BN coefs broadcast from LDS.
// ---------------------------------------------------------------------------
__global__ __launch_bounds__(256) void finalize_kernel(
    const float* __restrict__ x, const float* __restrict__ gamma,
    const float* __restrict__ beta, const float* __restrict__ bias1,
    const float* __restrict__ alpha, const float* __restrict__ bias2,
    const char* __restrict__ ws, float* __restrict__ out) {
  __shared__ u64   ldsT[256][4];   // [o][plane]
  __shared__ f32x4 ldsC[256];      // {2*cA, cB, alpha, bias2}

  int t = threadIdx.x;
  {
    const u64* T = (const u64*)(ws + OFF_T);
#pragma unroll
    for (int q = 0; q < 4; ++q) ldsT[t][q] = T[q * 256 + t];

    const float*     scale = (const float*)(ws + OFF_SCALE);
    const long long* sumd  = (const long long*)(ws + OFF_SUMD);
    const long long* sumd2 = (const long long*)(ws + OFF_SUMD2);
    double inv  = 1.0 / (double)kP;
    double md   = (double)sumd[t] * inv;
    double e2   = (double)sumd2[t] * inv;
    double vard = e2 - md * md;
    float sc  = scale[t];
    float mu  = sc * (float)md;
    float var = sc * sc * (float)vard;
    float rs  = rsqrtf(var + 1e-5f);
    float g   = gamma[t];
    float cA  = g * rs * sc;
    float cB  = beta[t] - g * rs * mu + bias1[t];
    f32x4 cc; cc.x = 2.0f * cA; cc.y = cB; cc.z = alpha[t]; cc.w = bias2[t];
    ldsC[t] = cc;
  }
  __syncthreads();

  int k    = __builtin_amdgcn_readfirstlane(t >> 6);
  int lane = t & 63;
  u32 p0 = (u32)blockIdx.x * (u32)kTile + 4u * (u32)lane;
  u32 n  = p0 / kHW;
  u32 hw = p0 - n * kHW;

  const u64* S = (const u64*)(ws + OFF_S);
  U64x2 a0 = *(const U64x2*)&S[p0],          b0 = *(const U64x2*)&S[p0 + 2];
  U64x2 a1 = *(const U64x2*)&S[kP + p0],     b1 = *(const U64x2*)&S[kP + p0 + 2];
  U64x2 a2 = *(const U64x2*)&S[2 * kP + p0], b2 = *(const U64x2*)&S[2 * kP + p0 + 2];
  U64x2 a3 = *(const U64x2*)&S[3 * kP + p0], b3 = *(const U64x2*)&S[3 * kP + p0 + 2];

  const float* xp = x   + (size_t)(n * kC + k * 64) * kHW + hw;
  float*       op = out + (size_t)(n * kC + k * 64) * kHW + hw;

#pragma unroll 4
  for (int i = 0; i < 64; ++i) {
    int o = k * 64 + i;                // wave-uniform -> LDS broadcast
    u64 w0 = ldsT[o][0], w1 = ldsT[o][1], w2 = ldsT[o][2], w3 = ldsT[o][3];
    f32x4 cc = ldsC[o];
    f32x4 xv = *(const f32x4*)(xp + (size_t)i * kHW);   // 1 KB/wave contiguous
    int k0 = __popcll(a0.x ^ w0) + __popcll(a1.x ^ w1) +
             __popcll(a2.x ^ w2) + __popcll(a3.x ^ w3);
    int k1 = __popcll(a0.y ^ w0) + __popcll(a1.y ^ w1) +
             __popcll(a2.y ^ w2) + __popcll(a3.y ^ w3);
    int k2 = __popcll(b0.x ^ w0) + __popcll(b1.x ^ w1) +
             __popcll(b2.x ^ w2) + __popcll(b3.x ^ w3);
    int k3 = __popcll(b0.y ^ w0) + __popcll(b1.y ^ w1) +
             __popcll(b2.y ^ w2) + __popcll(b3.y ^ w3);
    float u0 = fmaf(cc.x, (float)(128 - k0), cc.y) + xv.x;
    float u1 = fmaf(cc.x, (float)(128 - k1), cc.y) + xv.y;
    float u2 = fmaf(cc.x, (float)(128 - k2), cc.y) + xv.z;
    float u3 = fmaf(cc.x, (float)(128 - k3), cc.y) + xv.w;
    f32x4 r;
    r.x = (u0 > 0.0f ? u0 : cc.z * u0) + cc.w;
    r.y = (u1 > 0.0f ? u1 : cc.z * u1) + cc.w;
    r.z = (u2 > 0.0f ? u2 : cc.z * u2) + cc.w;
    r.w = (u3 > 0.0f ? u3 : cc.z * u3) + cc.w;
    __builtin_nontemporal_store(r, (f32x4*)(op + (size_t)i * kHW));
  }
}

extern "C" void kernel_launch(void* const* d_in, const int* in_sizes, int n_in,
                              void* d_out, int out_size, void* d_ws, size_t ws_size,
                              hipStream_t stream) {
  const float* x     = (const float*)d_in[0];
  const float* bias0 = (const float*)d_in[1];
  const float* w     = (const float*)d_in[2];
  const float* gamma = (const float*)d_in[3];
  const float* beta  = (const float*)d_in[4];
  const float* bias1 = (const float*)d_in[5];
  const float* alpha = (const float*)d_in[6];
  const float* bias2 = (const float*)d_in[7];
  float* out = (float*)d_out;
  char*  ws  = (char*)d_ws;

  hipLaunchKernelGGL(prep_kernel, dim3(16), dim3(256), 0, stream, w, ws);
  hipLaunchKernelGGL(pack_kernel, dim3(kBlkT), dim3(256), 0, stream,
                     x, bias0, ws);
  hipLaunchKernelGGL(stats_kernel, dim3(kBlkT), dim3(256), 0, stream, ws);
  hipLaunchKernelGGL(reduce_kernel, dim3(kRedBlk), dim3(256), 0, stream, ws);
  hipLaunchKernelGGL(finalize_kernel, dim3(kBlkT), dim3(256), 0, stream,
                     x, gamma, beta, bias1, alpha, bias2, ws, out);
}